// Round 7
// baseline (660.384 us; speedup 1.0000x reference)
//
#include <hip/hip_runtime.h>
#include <math.h>

#define NN 50000
#define NE 1200000
#define FIN 128
#define FE 32
#define H 78
#define HP 80
#define ETOT (NE + NN)
#define NG (HP / 4)          // 20 float4 groups per node row

#define SCAN_B 256
#define SCAN_C 4
#define SCAN_TILE (SCAN_B * SCAN_C)                 // 1024
#define NBLK ((NN + SCAN_TILE - 1) / SCAN_TILE)     // 49

// ---------------- dense node GEMM, j-split x2 for occupancy ----------------
// thread t -> (node n = t>>1, half = t&1); each half computes 39 columns.
// Partial attention dots reduced across the lane pair via shfl_xor.
template<int K, int LDA>
__global__ void gemm_node(const float* __restrict__ A, const float* __restrict__ W,
                          const float* __restrict__ as, const float* __restrict__ ad,
                          float* __restrict__ C, float* __restrict__ asv,
                          float* __restrict__ adv) {
  int t = blockIdx.x * blockDim.x + threadIdx.x;
  int n = t >> 1;
  int half = t & 1;
  if (n >= NN) return;
  const int JH = 39;
  const int j0 = half * JH;
  const float* a = A + (size_t)n * LDA;
  float acc[JH];
#pragma unroll
  for (int j = 0; j < JH; ++j) acc[j] = 0.f;
  int k = 0;
  for (; k + 4 <= K; k += 4) {
    float4 av = *reinterpret_cast<const float4*>(a + k);
    const float* w0 = W + (size_t)k * H + j0;
#pragma unroll
    for (int j = 0; j < JH; ++j) acc[j] = fmaf(av.x, w0[j], acc[j]);
#pragma unroll
    for (int j = 0; j < JH; ++j) acc[j] = fmaf(av.y, w0[H + j], acc[j]);
#pragma unroll
    for (int j = 0; j < JH; ++j) acc[j] = fmaf(av.z, w0[2 * H + j], acc[j]);
#pragma unroll
    for (int j = 0; j < JH; ++j) acc[j] = fmaf(av.w, w0[3 * H + j], acc[j]);
  }
  for (; k < K; ++k) {
    float av = a[k];
    const float* w0 = W + (size_t)k * H + j0;
#pragma unroll
    for (int j = 0; j < JH; ++j) acc[j] = fmaf(av, w0[j], acc[j]);
  }
  float* c = C + (size_t)n * HP + j0;
#pragma unroll
  for (int j = 0; j < JH; ++j) c[j] = acc[j];
  if (half) { c[JH] = 0.f; c[JH + 1] = 0.f; }   // cols 78,79 zero
  float sa = 0.f, sd = 0.f;
#pragma unroll
  for (int j = 0; j < JH; ++j) {
    sa = fmaf(acc[j], as[j0 + j], sa);
    sd = fmaf(acc[j], ad[j0 + j], sd);
  }
  sa += __shfl_xor(sa, 1);
  sd += __shfl_xor(sd, 1);
  if (!half) { asv[n] = sa; adv[n] = sd; }
}

// ---------------- CSR build ----------------
__global__ void zero_deg(int* __restrict__ deg) {
  int n = blockIdx.x * blockDim.x + threadIdx.x;
  if (n < NN) deg[n] = 0;
}

__global__ void deg_count(const int* __restrict__ ei, int* __restrict__ deg) {
  int i = blockIdx.x * blockDim.x + threadIdx.x;
  if (i >= ETOT) return;
  int dst = (i < NE) ? ei[NE + i] : (i - NE);
  atomicAdd(deg + dst, 1);
}

__global__ void scan1(const int* __restrict__ deg, int* __restrict__ bsum) {
  __shared__ int sh[SCAN_B];
  int b = blockIdx.x, t = threadIdx.x;
  int base = b * SCAN_TILE + t * SCAN_C;
  int s = 0;
#pragma unroll
  for (int k = 0; k < SCAN_C; ++k) {
    int i = base + k;
    if (i < NN) s += deg[i];
  }
  sh[t] = s;
  __syncthreads();
  for (int off = SCAN_B / 2; off > 0; off >>= 1) {
    if (t < off) sh[t] += sh[t + off];
    __syncthreads();
  }
  if (t == 0) bsum[b] = sh[0];
}

__global__ void scan2(const int* __restrict__ bsum, int* __restrict__ boff) {
  __shared__ int sh[64];
  int t = threadIdx.x;
  sh[t] = (t < NBLK) ? bsum[t] : 0;
  __syncthreads();
  for (int off = 1; off < 64; off <<= 1) {
    int v = (t >= off) ? sh[t - off] : 0;
    __syncthreads();
    sh[t] += v;
    __syncthreads();
  }
  if (t < NBLK) boff[t] = (t == 0) ? 0 : sh[t - 1];
}

__global__ void scan3(const int* __restrict__ deg, const int* __restrict__ boff,
                      int* __restrict__ rowptr, int* __restrict__ cursor) {
  __shared__ int sh[SCAN_B];
  int b = blockIdx.x, t = threadIdx.x;
  int base = b * SCAN_TILE + t * SCAN_C;
  int v[SCAN_C];
  int s = 0;
#pragma unroll
  for (int k = 0; k < SCAN_C; ++k) {
    int i = base + k;
    v[k] = (i < NN) ? deg[i] : 0;
    s += v[k];
  }
  sh[t] = s;
  __syncthreads();
  for (int off = 1; off < SCAN_B; off <<= 1) {
    int u = (t >= off) ? sh[t - off] : 0;
    __syncthreads();
    sh[t] += u;
    __syncthreads();
  }
  int run = boff[b] + ((t == 0) ? 0 : sh[t - 1]);
#pragma unroll
  for (int k = 0; k < SCAN_C; ++k) {
    int i = base + k;
    if (i < NN) {
      rowptr[i] = run;
      cursor[i] = run;
      run += v[k];
    }
  }
  if (b == 0 && t == 0) rowptr[NN] = ETOT;
}

__global__ void csr_fill(const int* __restrict__ ei, int* __restrict__ cursor,
                         int* __restrict__ srcs) {
  int i = blockIdx.x * blockDim.x + threadIdx.x;
  if (i >= ETOT) return;
  int src, dst;
  if (i < NE) { src = ei[i]; dst = ei[NE + i]; }
  else { src = dst = i - NE; }
  int pos = atomicAdd(cursor + dst, 1);
  srcs[pos] = src;
}

// ---------------- per-destination ONLINE softmax (1 random-gather pass) ----------------
__global__ void softmax_csr(const int* __restrict__ rowptr, const int* __restrict__ srcs,
                            const float* __restrict__ asv, const float* __restrict__ adv,
                            float* __restrict__ aw) {
  int n = blockIdx.x * blockDim.x + threadIdx.x;
  if (n >= NN) return;
  int r0 = rowptr[n], r1 = rowptr[n + 1];
  float advn = adv[n];
  float m = -INFINITY, s = 0.f;
  for (int p = r0; p < r1; ++p) {
    float e = asv[srcs[p]] + advn;
    e = e > 0.f ? e : 0.2f * e;
    aw[p] = e;
    if (e > m) {
      s = s * __expf(m - e);   // exp(-inf)=0 handles first iteration
      m = e;
    }
    s += __expf(e - m);
  }
  float inv = 1.f / (s + 1e-16f);
  for (int p = r0; p < r1; ++p) aw[p] = __expf(aw[p] - m) * inv;
}

// ---------------- gather-based aggregation; bias (+optional relu) fused ----------------
template<int RELU>
__global__ void agg_csr(const int* __restrict__ rowptr, const int* __restrict__ srcs,
                        const float* __restrict__ aw, const float* __restrict__ h,
                        const float* __restrict__ biasp, float* __restrict__ outp) {
  int t = blockIdx.x * blockDim.x + threadIdx.x;
  if (t >= NN * NG) return;
  int n = t / NG;
  int g = t - n * NG;
  int r0 = rowptr[n], r1 = rowptr[n + 1];
  float ax = 0.f, ay = 0.f, az = 0.f, aww = 0.f;
  const float* hb = h + (size_t)g * 4;
  for (int p = r0; p < r1; ++p) {
    float al = aw[p];
    int s = srcs[p];
    float4 hv = *reinterpret_cast<const float4*>(hb + (size_t)s * HP);
    ax += al * hv.x;
    ay += al * hv.y;
    az += al * hv.z;
    aww += al * hv.w;
  }
  float4 bv = *reinterpret_cast<const float4*>(biasp + g * 4);
  float4 r;
  r.x = ax + bv.x; r.y = ay + bv.y; r.z = az + bv.z; r.w = aww + bv.w;
  if (RELU) {
    r.x = fmaxf(r.x, 0.f); r.y = fmaxf(r.y, 0.f);
    r.z = fmaxf(r.z, 0.f); r.w = fmaxf(r.w, 0.f);
  }
  *reinterpret_cast<float4*>(outp + (size_t)n * HP + g * 4) = r;
}

__global__ void prep_bias(const float* __restrict__ b1, const float* __restrict__ b2,
                          float* __restrict__ b1p, float* __restrict__ b2p) {
  int t = threadIdx.x;
  if (t < HP) {
    b1p[t] = (t < H) ? b1[t] : 0.f;
    b2p[t] = (t < H) ? b2[t] : 0.f;
  }
}

__global__ void final_node(const float* __restrict__ h2f, const float* __restrict__ Wf,
                           float* __restrict__ u, float* __restrict__ v) {
  int n = blockIdx.x * blockDim.x + threadIdx.x;
  if (n >= NN) return;
  const float* r = h2f + (size_t)n * HP;
  float su = 0.f, sv = 0.f;
#pragma unroll
  for (int j = 0; j < H; ++j) {
    float hv = r[j];
    su += hv * Wf[j];
    sv += hv * Wf[H + j];
  }
  u[n] = su;
  v[n] = sv;
}

__global__ void mk_wproj(const float* __restrict__ Wm2, const float* __restrict__ bm2,
                         const float* __restrict__ Wf, const float* __restrict__ bf,
                         float* __restrict__ wpc) {
  int k = threadIdx.x;
  if (k < H) {
    float s = 0.f;
    for (int j = 0; j < H; ++j) s += Wm2[k * H + j] * Wf[2 * H + j];
    wpc[k] = s;
  } else if (k == H) {
    float s = 0.f;
    for (int j = 0; j < H; ++j) s += bm2[j] * Wf[2 * H + j];
    wpc[H] = s + bf[0];
  }
}

// ---------------- edge head: accumulators PINNED in VGPRs via no-op asm --------------
// The asm "+v" pins make every acc[j] live at the end of each k-chunk: the compiler
// cannot loop-interchange back to j-outer form or re-read ea (rounds 3-6 pathology).
__global__ void final_edge(const int* __restrict__ ei, const float* __restrict__ ea,
                           const float* __restrict__ Wm1, const float* __restrict__ bm1,
                           const float* __restrict__ wpc, const float* __restrict__ u,
                           const float* __restrict__ v, float* __restrict__ out) {
  int e = blockIdx.x * blockDim.x + threadIdx.x;
  if (e >= NE) return;
  const float* a = ea + (size_t)e * FE;
  float acc[H];
#pragma unroll
  for (int j = 0; j < H; ++j) acc[j] = 0.f;
#pragma unroll
  for (int k = 0; k < FE; k += 4) {
    float4 av = *reinterpret_cast<const float4*>(a + k);
    const float* w0 = Wm1 + (size_t)k * H;
#pragma unroll
    for (int j = 0; j < H; ++j) acc[j] = fmaf(av.x, w0[j], acc[j]);
#pragma unroll
    for (int j = 0; j < H; ++j) acc[j] = fmaf(av.y, w0[H + j], acc[j]);
#pragma unroll
    for (int j = 0; j < H; ++j) acc[j] = fmaf(av.z, w0[2 * H + j], acc[j]);
#pragma unroll
    for (int j = 0; j < H; ++j) acc[j] = fmaf(av.w, w0[3 * H + j], acc[j]);
#pragma unroll
    for (int j = 0; j < H; ++j) asm volatile("" : "+v"(acc[j]));
  }
  int s = ei[e], d = ei[NE + e];
  float base = u[s] + v[d] + wpc[H];
  float r0 = 0.f, r1 = 0.f, r2 = 0.f, r3 = 0.f;
#pragma unroll
  for (int j = 0; j + 4 <= H; j += 4) {
    r0 = fmaf(fmaxf(acc[j + 0] + bm1[j + 0], 0.f), wpc[j + 0], r0);
    r1 = fmaf(fmaxf(acc[j + 1] + bm1[j + 1], 0.f), wpc[j + 1], r1);
    r2 = fmaf(fmaxf(acc[j + 2] + bm1[j + 2], 0.f), wpc[j + 2], r2);
    r3 = fmaf(fmaxf(acc[j + 3] + bm1[j + 3], 0.f), wpc[j + 3], r3);
  }
  r0 = fmaf(fmaxf(acc[76] + bm1[76], 0.f), wpc[76], r0);
  r1 = fmaf(fmaxf(acc[77] + bm1[77], 0.f), wpc[77], r1);
  out[e] = base + (r0 + r1) + (r2 + r3);
}

extern "C" void kernel_launch(void* const* d_in, const int* in_sizes, int n_in,
                              void* d_out, int out_size, void* d_ws, size_t ws_size,
                              hipStream_t stream) {
  const float* x   = (const float*)d_in[0];
  const int*   ei  = (const int*)d_in[1];
  const float* ea  = (const float*)d_in[2];
  const float* W1  = (const float*)d_in[3];
  const float* as1 = (const float*)d_in[4];
  const float* ad1 = (const float*)d_in[5];
  const float* b1  = (const float*)d_in[6];
  const float* W2  = (const float*)d_in[7];
  const float* as2 = (const float*)d_in[8];
  const float* ad2 = (const float*)d_in[9];
  const float* b2  = (const float*)d_in[10];
  const float* Wm1 = (const float*)d_in[11];
  const float* bm1 = (const float*)d_in[12];
  const float* Wm2 = (const float*)d_in[13];
  const float* bm2 = (const float*)d_in[14];
  const float* Wf  = (const float*)d_in[15];
  const float* bf  = (const float*)d_in[16];
  float* out = (float*)d_out;

  float* w = (float*)d_ws;
  float* h1   = w; w += (size_t)NN * HP;   // layer1 h; later reused as layer2 agg out
  float* bufB = w; w += (size_t)NN * HP;   // layer1 agg out (h1r) = layer2 gemm input
  float* h2   = w; w += (size_t)NN * HP;
  float* asv  = w; w += NN;
  float* adv  = w; w += NN;
  float* uu   = w; w += NN;
  float* vv   = w; w += NN;
  float* wpc  = w; w += HP;
  float* b1p  = w; w += HP;
  float* b2p  = w; w += HP;
  float* aw   = w; w += ETOT;
  int* deg    = (int*)w; w += NN;
  int* rowptr = (int*)w; w += NN + 1;
  int* cursor = (int*)w; w += NN;
  int* srcs   = (int*)w; w += ETOT;
  int* bsum   = (int*)w; w += NBLK;
  int* boff   = (int*)w; w += NBLK;

  const int B = 256;
  dim3 gN((NN + B - 1) / B);
  dim3 gN2((NN * 2 + B - 1) / B);
  dim3 gE((ETOT + B - 1) / B);
  dim3 gA((NN * NG + B - 1) / B);
  dim3 gEo((NE + B - 1) / B);

  // ---- CSR build (dst-sorted) ----
  zero_deg<<<gN, B, 0, stream>>>(deg);
  deg_count<<<gE, B, 0, stream>>>(ei, deg);
  scan1<<<NBLK, SCAN_B, 0, stream>>>(deg, bsum);
  scan2<<<1, 64, 0, stream>>>(bsum, boff);
  scan3<<<NBLK, SCAN_B, 0, stream>>>(deg, boff, rowptr, cursor);
  csr_fill<<<gE, B, 0, stream>>>(ei, cursor, srcs);
  prep_bias<<<1, 128, 0, stream>>>(b1, b2, b1p, b2p);

  // ---- layer 1 ----
  gemm_node<FIN, FIN><<<gN2, B, 0, stream>>>(x, W1, as1, ad1, h1, asv, adv);
  softmax_csr<<<gN, B, 0, stream>>>(rowptr, srcs, asv, adv, aw);
  agg_csr<1><<<gA, B, 0, stream>>>(rowptr, srcs, aw, h1, b1p, bufB);

  // ---- layer 2 ----
  gemm_node<H, HP><<<gN2, B, 0, stream>>>(bufB, W2, as2, ad2, h2, asv, adv);
  softmax_csr<<<gN, B, 0, stream>>>(rowptr, srcs, asv, adv, aw);
  agg_csr<0><<<gA, B, 0, stream>>>(rowptr, srcs, aw, h2, b2p, h1);
  final_node<<<gN, B, 0, stream>>>(h1, Wf, uu, vv);

  // ---- edge head ----
  mk_wproj<<<1, 128, 0, stream>>>(Wm2, bm2, Wf, bf, wpc);
  final_edge<<<gEo, B, 0, stream>>>(ei, ea, Wm1, bm1, wpc, uu, vv, out);
}

// Round 8
// 509.320 us; speedup vs baseline: 1.2966x; 1.2966x over previous
//
#include <hip/hip_runtime.h>
#include <math.h>

#define NN 50000
#define NE 1200000
#define FIN 128
#define FE 32
#define H 78
#define HP 80
#define ETOT (NE + NN)
#define NG (HP / 4)          // 20 float4 groups per node row

#define SCAN_B 256
#define SCAN_C 4
#define SCAN_TILE (SCAN_B * SCAN_C)                 // 1024
#define NBLK ((NN + SCAN_TILE - 1) / SCAN_TILE)     // 49

typedef __attribute__((ext_vector_type(8))) short bf16x8;
typedef __attribute__((ext_vector_type(4))) float f32x4;

__device__ __forceinline__ unsigned short f2bf(float f) {   // RNE float->bf16
  unsigned u = __float_as_uint(f);
  return (unsigned short)((u + 0x7FFFu + ((u >> 16) & 1u)) >> 16);
}

// ---------------- dense node GEMM with fused attention-score epilogue ----------------
template<int K, int LDA>
__global__ void gemm_node(const float* __restrict__ A, const float* __restrict__ W,
                          const float* __restrict__ as, const float* __restrict__ ad,
                          float* __restrict__ C, float* __restrict__ asv,
                          float* __restrict__ adv) {
  int n = blockIdx.x * blockDim.x + threadIdx.x;
  if (n >= NN) return;
  const float* a = A + (size_t)n * LDA;
  float acc[H];
#pragma unroll
  for (int j = 0; j < H; ++j) acc[j] = 0.f;
  int k = 0;
  for (; k + 4 <= K; k += 4) {
    float4 av = *reinterpret_cast<const float4*>(a + k);
    const float* w0 = W + (size_t)k * H;
#pragma unroll
    for (int j = 0; j < H; ++j) acc[j] += av.x * w0[j];
#pragma unroll
    for (int j = 0; j < H; ++j) acc[j] += av.y * w0[H + j];
#pragma unroll
    for (int j = 0; j < H; ++j) acc[j] += av.z * w0[2 * H + j];
#pragma unroll
    for (int j = 0; j < H; ++j) acc[j] += av.w * w0[3 * H + j];
  }
  for (; k < K; ++k) {
    float av = a[k];
    const float* w0 = W + (size_t)k * H;
#pragma unroll
    for (int j = 0; j < H; ++j) acc[j] += av * w0[j];
  }
  float* c = C + (size_t)n * HP;
#pragma unroll
  for (int j = 0; j < H; ++j) c[j] = acc[j];
  c[H] = 0.f;
  c[H + 1] = 0.f;
  float sa = 0.f, sd = 0.f;
#pragma unroll
  for (int j = 0; j < H; ++j) {
    sa += acc[j] * as[j];
    sd += acc[j] * ad[j];
  }
  asv[n] = sa;
  adv[n] = sd;
}

// ---------------- CSR build ----------------
__global__ void zero_deg(int* __restrict__ deg) {
  int n = blockIdx.x * blockDim.x + threadIdx.x;
  if (n < NN) deg[n] = 0;
}

__global__ void deg_count(const int* __restrict__ ei, int* __restrict__ deg) {
  int i = blockIdx.x * blockDim.x + threadIdx.x;
  if (i >= ETOT) return;
  int dst = (i < NE) ? ei[NE + i] : (i - NE);
  atomicAdd(deg + dst, 1);
}

__global__ void scan1(const int* __restrict__ deg, int* __restrict__ bsum) {
  __shared__ int sh[SCAN_B];
  int b = blockIdx.x, t = threadIdx.x;
  int base = b * SCAN_TILE + t * SCAN_C;
  int s = 0;
#pragma unroll
  for (int k = 0; k < SCAN_C; ++k) {
    int i = base + k;
    if (i < NN) s += deg[i];
  }
  sh[t] = s;
  __syncthreads();
  for (int off = SCAN_B / 2; off > 0; off >>= 1) {
    if (t < off) sh[t] += sh[t + off];
    __syncthreads();
  }
  if (t == 0) bsum[b] = sh[0];
}

__global__ void scan2(const int* __restrict__ bsum, int* __restrict__ boff) {
  __shared__ int sh[64];
  int t = threadIdx.x;
  sh[t] = (t < NBLK) ? bsum[t] : 0;
  __syncthreads();
  for (int off = 1; off < 64; off <<= 1) {
    int v = (t >= off) ? sh[t - off] : 0;
    __syncthreads();
    sh[t] += v;
    __syncthreads();
  }
  if (t < NBLK) boff[t] = (t == 0) ? 0 : sh[t - 1];
}

__global__ void scan3(const int* __restrict__ deg, const int* __restrict__ boff,
                      int* __restrict__ rowptr, int* __restrict__ cursor) {
  __shared__ int sh[SCAN_B];
  int b = blockIdx.x, t = threadIdx.x;
  int base = b * SCAN_TILE + t * SCAN_C;
  int v[SCAN_C];
  int s = 0;
#pragma unroll
  for (int k = 0; k < SCAN_C; ++k) {
    int i = base + k;
    v[k] = (i < NN) ? deg[i] : 0;
    s += v[k];
  }
  sh[t] = s;
  __syncthreads();
  for (int off = 1; off < SCAN_B; off <<= 1) {
    int u = (t >= off) ? sh[t - off] : 0;
    __syncthreads();
    sh[t] += u;
    __syncthreads();
  }
  int run = boff[b] + ((t == 0) ? 0 : sh[t - 1]);
#pragma unroll
  for (int k = 0; k < SCAN_C; ++k) {
    int i = base + k;
    if (i < NN) {
      rowptr[i] = run;
      cursor[i] = run;
      run += v[k];
    }
  }
  if (b == 0 && t == 0) rowptr[NN] = ETOT;
}

__global__ void csr_fill(const int* __restrict__ ei, int* __restrict__ cursor,
                         int* __restrict__ srcs) {
  int i = blockIdx.x * blockDim.x + threadIdx.x;
  if (i >= ETOT) return;
  int src, dst;
  if (i < NE) { src = ei[i]; dst = ei[NE + i]; }
  else { src = dst = i - NE; }
  int pos = atomicAdd(cursor + dst, 1);
  srcs[pos] = src;
}

// ---------------- per-destination ONLINE softmax (1 random-gather pass) ----------------
__global__ void softmax_csr(const int* __restrict__ rowptr, const int* __restrict__ srcs,
                            const float* __restrict__ asv, const float* __restrict__ adv,
                            float* __restrict__ aw) {
  int n = blockIdx.x * blockDim.x + threadIdx.x;
  if (n >= NN) return;
  int r0 = rowptr[n], r1 = rowptr[n + 1];
  float advn = adv[n];
  float m = -INFINITY, s = 0.f;
  for (int p = r0; p < r1; ++p) {
    float e = asv[srcs[p]] + advn;
    e = e > 0.f ? e : 0.2f * e;
    aw[p] = e;
    if (e > m) {
      s = s * __expf(m - e);   // exp(-inf)=0 handles first iteration
      m = e;
    }
    s += __expf(e - m);
  }
  float inv = 1.f / (s + 1e-16f);
  for (int p = r0; p < r1; ++p) aw[p] = __expf(aw[p] - m) * inv;
}

// ---------------- gather-based aggregation; bias (+optional relu) fused ----------------
template<int RELU>
__global__ void agg_csr(const int* __restrict__ rowptr, const int* __restrict__ srcs,
                        const float* __restrict__ aw, const float* __restrict__ h,
                        const float* __restrict__ biasp, float* __restrict__ outp) {
  int t = blockIdx.x * blockDim.x + threadIdx.x;
  if (t >= NN * NG) return;
  int n = t / NG;
  int g = t - n * NG;
  int r0 = rowptr[n], r1 = rowptr[n + 1];
  float ax = 0.f, ay = 0.f, az = 0.f, aww = 0.f;
  const float* hb = h + (size_t)g * 4;
  for (int p = r0; p < r1; ++p) {
    float al = aw[p];
    int s = srcs[p];
    float4 hv = *reinterpret_cast<const float4*>(hb + (size_t)s * HP);
    ax += al * hv.x;
    ay += al * hv.y;
    az += al * hv.z;
    aww += al * hv.w;
  }
  float4 bv = *reinterpret_cast<const float4*>(biasp + g * 4);
  float4 r;
  r.x = ax + bv.x; r.y = ay + bv.y; r.z = az + bv.z; r.w = aww + bv.w;
  if (RELU) {
    r.x = fmaxf(r.x, 0.f); r.y = fmaxf(r.y, 0.f);
    r.z = fmaxf(r.z, 0.f); r.w = fmaxf(r.w, 0.f);
  }
  *reinterpret_cast<float4*>(outp + (size_t)n * HP + g * 4) = r;
}

__global__ void prep_bias(const float* __restrict__ b1, const float* __restrict__ b2,
                          float* __restrict__ b1p, float* __restrict__ b2p) {
  int t = threadIdx.x;
  if (t < HP) {
    b1p[t] = (t < H) ? b1[t] : 0.f;
    b2p[t] = (t < H) ? b2[t] : 0.f;
  }
}

__global__ void final_node(const float* __restrict__ h2f, const float* __restrict__ Wf,
                           float* __restrict__ u, float* __restrict__ v) {
  int n = blockIdx.x * blockDim.x + threadIdx.x;
  if (n >= NN) return;
  const float* r = h2f + (size_t)n * HP;
  float su = 0.f, sv = 0.f;
#pragma unroll
  for (int j = 0; j < H; ++j) {
    float hv = r[j];
    su += hv * Wf[j];
    sv += hv * Wf[H + j];
  }
  u[n] = su;
  v[n] = sv;
}

__global__ void mk_wproj(const float* __restrict__ Wm2, const float* __restrict__ bm2,
                         const float* __restrict__ Wf, const float* __restrict__ bf,
                         float* __restrict__ wpc) {
  int k = threadIdx.x;
  if (k < H) {
    float s = 0.f;
    for (int j = 0; j < H; ++j) s += Wm2[k * H + j] * Wf[2 * H + j];
    wpc[k] = s;
  } else if (k == H) {
    float s = 0.f;
    for (int j = 0; j < H; ++j) s += bm2[j] * Wf[2 * H + j];
    wpc[H] = s + bf[0];
  }
}

// ---------------- edge head via MFMA: ea[E x 32] @ Wm1[32 x 78] -------------
// mfma_f32_16x16x32_bf16: K=32 == FE. One wave = 4 tiles of 16 edges.
// A-frag: lane holds ea[ebase + (lane&15)][ (lane>>4)*8 .. +8 ] (contig, ->bf16)
// B-frag g: lane holds Wm1[(lane>>4)*8+e][16g + (lane&15)] (strided, preloaded)
// C/D: col = lane&15 (HW-verified), row(edge) = (lane>>4)*4 + reg.
// Epilogue fp32: esum = sum_cols relu(c + bm1[col]) * wpc[col]; butterfly over
// the 16-lane col group; lanes lane&15<4 store edge results.
#define FE_WAVES 18750          // NE / 64 edges per wave
__global__ __launch_bounds__(256)
void final_edge_mfma(const int* __restrict__ ei, const float* __restrict__ ea,
                     const float* __restrict__ Wm1, const float* __restrict__ bm1,
                     const float* __restrict__ wpc, const float* __restrict__ u,
                     const float* __restrict__ v, float* __restrict__ out) {
  int lane = threadIdx.x & 63;
  long gw = (long)blockIdx.x * 4 + (threadIdx.x >> 6);
  if (gw >= FE_WAVES) return;
  int l15 = lane & 15;
  int kg = lane >> 4;                    // k-group 0..3
  bf16x8 bfrag[5];
  float bm1c[5], wpcc[5];
#pragma unroll
  for (int g = 0; g < 5; ++g) {
    int col = g * 16 + l15;
    bool valid = col < H;
    bm1c[g] = valid ? bm1[col] : 0.f;
    wpcc[g] = valid ? wpc[col] : 0.f;
#pragma unroll
    for (int e = 0; e < 8; ++e) {
      int kk = kg * 8 + e;
      bfrag[g][e] = valid ? (short)f2bf(Wm1[kk * H + col]) : (short)0;
    }
  }
  float basec = wpc[H];
  int e0 = (int)(gw * 64);
#pragma unroll
  for (int t = 0; t < 4; ++t) {
    int ebase = e0 + t * 16;
    const float* ar = ea + (size_t)(ebase + l15) * FE + kg * 8;
    float4 f0 = *reinterpret_cast<const float4*>(ar);
    float4 f1 = *reinterpret_cast<const float4*>(ar + 4);
    bf16x8 afrag;
    afrag[0] = (short)f2bf(f0.x); afrag[1] = (short)f2bf(f0.y);
    afrag[2] = (short)f2bf(f0.z); afrag[3] = (short)f2bf(f0.w);
    afrag[4] = (short)f2bf(f1.x); afrag[5] = (short)f2bf(f1.y);
    afrag[6] = (short)f2bf(f1.z); afrag[7] = (short)f2bf(f1.w);
    float es0 = 0.f, es1 = 0.f, es2 = 0.f, es3 = 0.f;
#pragma unroll
    for (int g = 0; g < 5; ++g) {
      f32x4 c = {0.f, 0.f, 0.f, 0.f};
      c = __builtin_amdgcn_mfma_f32_16x16x32_bf16(afrag, bfrag[g], c, 0, 0, 0);
      es0 = fmaf(fmaxf(c[0] + bm1c[g], 0.f), wpcc[g], es0);
      es1 = fmaf(fmaxf(c[1] + bm1c[g], 0.f), wpcc[g], es1);
      es2 = fmaf(fmaxf(c[2] + bm1c[g], 0.f), wpcc[g], es2);
      es3 = fmaf(fmaxf(c[3] + bm1c[g], 0.f), wpcc[g], es3);
    }
#pragma unroll
    for (int m = 1; m < 16; m <<= 1) {
      es0 += __shfl_xor(es0, m);
      es1 += __shfl_xor(es1, m);
      es2 += __shfl_xor(es2, m);
      es3 += __shfl_xor(es3, m);
    }
    if (l15 < 4) {
      float es = (l15 == 0) ? es0 : (l15 == 1) ? es1 : (l15 == 2) ? es2 : es3;
      int e = ebase + kg * 4 + l15;
      int s = ei[e], d = ei[NE + e];
      out[e] = es + u[s] + v[d] + basec;
    }
  }
}

extern "C" void kernel_launch(void* const* d_in, const int* in_sizes, int n_in,
                              void* d_out, int out_size, void* d_ws, size_t ws_size,
                              hipStream_t stream) {
  const float* x   = (const float*)d_in[0];
  const int*   ei  = (const int*)d_in[1];
  const float* ea  = (const float*)d_in[2];
  const float* W1  = (const float*)d_in[3];
  const float* as1 = (const float*)d_in[4];
  const float* ad1 = (const float*)d_in[5];
  const float* b1  = (const float*)d_in[6];
  const float* W2  = (const float*)d_in[7];
  const float* as2 = (const float*)d_in[8];
  const float* ad2 = (const float*)d_in[9];
  const float* b2  = (const float*)d_in[10];
  const float* Wm1 = (const float*)d_in[11];
  const float* bm1 = (const float*)d_in[12];
  const float* Wm2 = (const float*)d_in[13];
  const float* bm2 = (const float*)d_in[14];
  const float* Wf  = (const float*)d_in[15];
  const float* bf  = (const float*)d_in[16];
  float* out = (float*)d_out;

  float* w = (float*)d_ws;
  float* h1   = w; w += (size_t)NN * HP;   // layer1 h; later reused as layer2 agg out
  float* bufB = w; w += (size_t)NN * HP;   // layer1 agg out (h1r) = layer2 gemm input
  float* h2   = w; w += (size_t)NN * HP;
  float* asv  = w; w += NN;
  float* adv  = w; w += NN;
  float* uu   = w; w += NN;
  float* vv   = w; w += NN;
  float* wpc  = w; w += HP;
  float* b1p  = w; w += HP;
  float* b2p  = w; w += HP;
  float* aw   = w; w += ETOT;
  int* deg    = (int*)w; w += NN;
  int* rowptr = (int*)w; w += NN + 1;
  int* cursor = (int*)w; w += NN;
  int* srcs   = (int*)w; w += ETOT;
  int* bsum   = (int*)w; w += NBLK;
  int* boff   = (int*)w; w += NBLK;

  const int B = 256;
  dim3 gN((NN + B - 1) / B);
  dim3 gE((ETOT + B - 1) / B);
  dim3 gA((NN * NG + B - 1) / B);
  dim3 gFE((FE_WAVES + 3) / 4);

  // ---- CSR build (dst-sorted) ----
  zero_deg<<<gN, B, 0, stream>>>(deg);
  deg_count<<<gE, B, 0, stream>>>(ei, deg);
  scan1<<<NBLK, SCAN_B, 0, stream>>>(deg, bsum);
  scan2<<<1, 64, 0, stream>>>(bsum, boff);
  scan3<<<NBLK, SCAN_B, 0, stream>>>(deg, boff, rowptr, cursor);
  csr_fill<<<gE, B, 0, stream>>>(ei, cursor, srcs);
  prep_bias<<<1, 128, 0, stream>>>(b1, b2, b1p, b2p);

  // ---- layer 1 ----
  gemm_node<FIN, FIN><<<gN, B, 0, stream>>>(x, W1, as1, ad1, h1, asv, adv);
  softmax_csr<<<gN, B, 0, stream>>>(rowptr, srcs, asv, adv, aw);
  agg_csr<1><<<gA, B, 0, stream>>>(rowptr, srcs, aw, h1, b1p, bufB);

  // ---- layer 2 ----
  gemm_node<H, HP><<<gN, B, 0, stream>>>(bufB, W2, as2, ad2, h2, asv, adv);
  softmax_csr<<<gN, B, 0, stream>>>(rowptr, srcs, asv, adv, aw);
  agg_csr<0><<<gA, B, 0, stream>>>(rowptr, srcs, aw, h2, b2p, h1);
  final_node<<<gN, B, 0, stream>>>(h1, Wf, uu, vv);

  // ---- edge head ----
  mk_wproj<<<1, 128, 0, stream>>>(Wm2, bm2, Wf, bf, wpc);
  final_edge_mfma<<<gFE, B, 0, stream>>>(ei, ea, Wm1, bm1, wpc, uu, vv, out);
}